// Round 1
// baseline (589.159 us; speedup 1.0000x reference)
//
#include <hip/hip_runtime.h>
#include <hip/hip_bf16.h>
#include <stdint.h>

// FourBranchFork: h = sum_b (x @ ws_b.T) @ d_b.T ; LN(h)
// Collapsed: G[j,i] = sum_b sum_k d_b[j,k]*ws_b[k,i]  (2048x2048, K=14336)
//            h[n,j] = sum_i x[n,i]*G[j,i]             (8192x2048, K=2048)
// R5: 256x256-tile 8-wave GEMM core with 4-deep K-subtile ring, counted
//     vmcnt(12) pipeline (T3+T4), XOR-swizzled LDS both-sides (T2, 2-way max),
//     setprio around MFMA cluster (T5). Replaces the m97-style 2-barrier core
//     (ceiling ~900 TF) for both stage B and stage C.

typedef unsigned short u16;
typedef __bf16 bf16x8 __attribute__((ext_vector_type(8)));
typedef float f32x4 __attribute__((ext_vector_type(4)));

#define H 2048
#define KTOT 14336

__device__ __forceinline__ u16 f2b(float f) {
    union { float f; uint32_t u; } v; v.f = f;
    uint32_t u = v.u;
    return (u16)((u + 0x7fffu + ((u >> 16) & 1u)) >> 16);  // RNE
}

__device__ __forceinline__ void gld16(const u16* g, u16* l) {
    __builtin_amdgcn_global_load_lds((__attribute__((address_space(1))) void*)g,
                                     (__attribute__((address_space(3))) void*)l,
                                     16, 0, 0);
}

// ---- fused relayout: pack d_b's -> A_cat bf16, cast x -> Xb bf16 ----
// block ranges: dq [0,16384) dz [16384,24576) db [24576,26624) da [26624,28672)
//               x  [28672,36864)
__global__ __launch_bounds__(256) void prep_pack(const float* __restrict__ dq,
                                                 const float* __restrict__ dz,
                                                 const float* __restrict__ db,
                                                 const float* __restrict__ da,
                                                 const float* __restrict__ x,
                                                 u16* __restrict__ Acat,
                                                 u16* __restrict__ Xb) {
    int bid = blockIdx.x;
    if (bid >= 28672) {   // cast x: 8 elems/thread
        size_t i = (((size_t)(bid - 28672)) * 256 + threadIdx.x) * 8;
        float4 a = *(const float4*)(x + i);
        float4 b = *(const float4*)(x + i + 4);
        uint32_t p0 = (uint32_t)f2b(a.x) | ((uint32_t)f2b(a.y) << 16);
        uint32_t p1 = (uint32_t)f2b(a.z) | ((uint32_t)f2b(a.w) << 16);
        uint32_t p2 = (uint32_t)f2b(b.x) | ((uint32_t)f2b(b.y) << 16);
        uint32_t p3 = (uint32_t)f2b(b.z) | ((uint32_t)f2b(b.w) << 16);
        *(uint4*)(Xb + i) = make_uint4(p0, p1, p2, p3);
        return;
    }
    const float* src; int kshift, kmask, coloff, base;
    if (bid < 16384)      { src = dq; kshift = 13; kmask = 8191; coloff = 0;     base = 0; }
    else if (bid < 24576) { src = dz; kshift = 12; kmask = 4095; coloff = 8192;  base = 16384; }
    else if (bid < 26624) { src = db; kshift = 10; kmask = 1023; coloff = 12288; base = 24576; }
    else                  { src = da; kshift = 10; kmask = 1023; coloff = 13312; base = 26624; }
    size_t idx = ((size_t)(bid - base) * 256 + threadIdx.x) * 4;
    int r = (int)(idx >> kshift);
    int c = (int)(idx & (size_t)kmask);
    float4 v = *(const float4*)(src + idx);
    ushort4 o = make_ushort4(f2b(v.x), f2b(v.y), f2b(v.z), f2b(v.w));
    *(ushort4*)(Acat + (size_t)r * KTOT + coloff + c) = o;
}

// ---- transpose+scale w_b [Kb,2048] fp32 * s -> B_cat[i][coloff+k] bf16 ----
__global__ __launch_bounds__(256) void prep_w(const float* __restrict__ wq, const float* __restrict__ sq,
                                              const float* __restrict__ wz, const float* __restrict__ sz,
                                              const float* __restrict__ wb, const float* __restrict__ sb,
                                              const float* __restrict__ wa, const float* __restrict__ sa,
                                              u16* __restrict__ dst) {
    __shared__ float tile[64][65];
    int by = blockIdx.y;
    const float* w; const float* s; int coloff, ybase;
    if (by < 128)      { w = wq; s = sq; coloff = 0;     ybase = 0; }
    else if (by < 192) { w = wz; s = sz; coloff = 8192;  ybase = 128; }
    else if (by < 208) { w = wb; s = sb; coloff = 12288; ybase = 192; }
    else               { w = wa; s = sa; coloff = 13312; ybase = 208; }
    const int t = threadIdx.x;
    const int i0 = blockIdx.x * 64, k0 = (by - ybase) * 64;
    const int c4 = (t & 15) * 4;          // column group within tile
    const int r0 = t >> 4;                // row within 16-row round
    const int sib = i0 >> 7;              // i 128-block (constant per tile)
#pragma unroll
    for (int rr = 0; rr < 4; ++rr) {
        int r = r0 + rr * 16;             // k-row within tile
        float sc = s[((k0 + r) >> 7) * (H / 128) + sib];
        float4 v = *(const float4*)(w + (size_t)(k0 + r) * H + i0 + c4);
        tile[r][c4 + 0] = v.x * sc;
        tile[r][c4 + 1] = v.y * sc;
        tile[r][c4 + 2] = v.z * sc;
        tile[r][c4 + 3] = v.w * sc;
    }
    __syncthreads();
#pragma unroll
    for (int rr = 0; rr < 4; ++rr) {
        int i = r0 + rr * 16;             // i-row within tile
        ushort4 o = make_ushort4(f2b(tile[c4 + 0][i]), f2b(tile[c4 + 1][i]),
                                 f2b(tile[c4 + 2][i]), f2b(tile[c4 + 3][i]));
        *(ushort4*)(dst + (size_t)(i0 + i) * KTOT + coloff + k0 + c4) = o;
    }
}

// ---- reduce 4 split-K fp32 partials -> G bf16 ----
__global__ __launch_bounds__(256) void reduce4_cvt(const float* __restrict__ P,
                                                   u16* __restrict__ G) {
    size_t i = ((size_t)blockIdx.x * 256 + threadIdx.x) * 4;
    const size_t st = (size_t)H * H;
    float4 a = *(const float4*)(P + i);
    float4 b = *(const float4*)(P + i + st);
    float4 c = *(const float4*)(P + i + 2 * st);
    float4 d = *(const float4*)(P + i + 3 * st);
    ushort4 o = make_ushort4(f2b(a.x + b.x + c.x + d.x),
                             f2b(a.y + b.y + c.y + d.y),
                             f2b(a.z + b.z + c.z + d.z),
                             f2b(a.w + b.w + c.w + d.w));
    *(ushort4*)(G + i) = o;
}

// ---------------- GEMM core (B^T form): C[m,n] = sum_k A[m,k]*B[n,k] ----------------
// 256x256 tile, 8 waves (2M x 4N), 512 threads. K processed in 32-wide subtiles.
// LDS: per operand a 4-slot ring of [256 rows][32 cols] bf16 (16 KB/slot), 128 KiB
// total. Within a 64-B row the 16-B chunk g is stored at g ^ ((row>>1)&3):
//   - staging pre-swizzles the GLOBAL source address (gld_lds dest stays linear)
//   - frag ds_read applies the same XOR -> 16-lane row-slices hit all 32 banks
//     exactly 2-way (free, m136).
// Pipeline: prefetch distance 3 subtiles; per iter: STAGE(s+3) -> vmcnt(12) ->
// s_barrier -> 12x ds_read_b128 -> setprio(1) 32 MFMA setprio(0) -> s_barrier.
// vmcnt never drains to 0 until the 3-iter epilogue (8 -> 4 -> 0).
__device__ __forceinline__ void gemm256_core(const u16* __restrict__ A,
                                             const u16* __restrict__ B,
                                             float* __restrict__ C,
                                             int lda, int ldb, int N, int klen) {
    __shared__ __align__(16) u16 As[32768];   // 64 KB: 4 slots x [256][32]
    __shared__ __align__(16) u16 Bs[32768];   // 64 KB
    const int t = threadIdx.x;                // 0..511
    const int lane = t & 63;
    const int wave = t >> 6;                  // 0..7
    const int wm = (wave >> 2) * 128;         // wave row: 0 / 128
    const int wn = (wave & 3) * 64;           // wave col: 0/64/128/192
    const size_t bm0 = (size_t)blockIdx.y * 256;
    const size_t bn0 = (size_t)blockIdx.x * 256;
    const int kstart = blockIdx.z * klen;
    const int NS = klen >> 5;                 // # of 32-wide K subtiles

    // staging: thread t covers 16 B of row (t>>2) [+128 for round 1] with the
    // pre-swizzled global k-chunk ((t&3) ^ ((t>>3)&3)).
    const int srow = t >> 2;
    const int scol = ((t & 3) ^ ((t >> 3) & 3)) * 8;
    const u16* ga = A + (bm0 + srow) * (size_t)lda + kstart + scol;
    const u16* gb = B + (bn0 + srow) * (size_t)ldb + kstart + scol;
    const size_t lda128 = (size_t)128 * lda;
    const size_t ldb128 = (size_t)128 * ldb;
    u16* const lwa = As + (t & ~63) * 8;      // wave-uniform linear LDS base
    u16* const lwb = Bs + (t & ~63) * 8;

    // fragment reads: lane holds op[row = l&15 (+16*frag)][k = (l>>4)*8 ..+8];
    // physical chunk = (l>>4) ^ ((row>>1)&3) — lane-pure since wm/wn/mi*16 drop mod 8.
    const int lr = lane & 15;
    const int fro = (((lane >> 4) ^ ((lr >> 1) & 3))) * 8;
    const u16* const fra = As + (wm + lr) * 32 + fro;
    const u16* const frb = Bs + (wn + lr) * 32 + fro;

    f32x4 acc[8][4] = {};

    auto STAGE = [&](int sidx) {
        const int sl = (sidx & 3) * 8192;     // slot offset in u16 (16 KB)
        const u16* a = ga + (size_t)sidx * 32;
        const u16* b = gb + (size_t)sidx * 32;
        gld16(a,          lwa + sl);
        gld16(a + lda128, lwa + sl + 4096);
        gld16(b,          lwb + sl);
        gld16(b + ldb128, lwb + sl + 4096);
    };
    auto COMPUTE = [&](int sidx) {
        const int sl = (sidx & 3) * 8192;
        const u16* fa = fra + sl;
        const u16* fb = frb + sl;
        bf16x8 af[8], bfr[4];
#pragma unroll
        for (int i = 0; i < 8; ++i) af[i] = *(const bf16x8*)(fa + i * 512);
#pragma unroll
        for (int j = 0; j < 4; ++j) bfr[j] = *(const bf16x8*)(fb + j * 512);
        __builtin_amdgcn_s_setprio(1);
#pragma unroll
        for (int mi = 0; mi < 8; ++mi)
#pragma unroll
            for (int ni = 0; ni < 4; ++ni)
                acc[mi][ni] = __builtin_amdgcn_mfma_f32_16x16x32_bf16(af[mi], bfr[ni], acc[mi][ni], 0, 0, 0);
        __builtin_amdgcn_s_setprio(0);
    };

    STAGE(0); STAGE(1); STAGE(2);             // 12 loads in flight
    int s = 0;
    for (; s < NS - 3; ++s) {
        STAGE(s + 3);                         // writes slot (s-1)&3: safe, prev
                                              // readers passed closing barrier
        asm volatile("s_waitcnt vmcnt(12)" ::: "memory");  // subtile s landed
        __builtin_amdgcn_s_barrier();         // everyone's s landed
        COMPUTE(s);
        __builtin_amdgcn_s_barrier();         // all done reading slot s&3
    }
    // epilogue: drain 8 -> 4 -> 0
    asm volatile("s_waitcnt vmcnt(8)" ::: "memory");
    __builtin_amdgcn_s_barrier();
    COMPUTE(s); ++s;
    __builtin_amdgcn_s_barrier();
    asm volatile("s_waitcnt vmcnt(4)" ::: "memory");
    __builtin_amdgcn_s_barrier();
    COMPUTE(s); ++s;
    __builtin_amdgcn_s_barrier();
    asm volatile("s_waitcnt vmcnt(0)" ::: "memory");
    __builtin_amdgcn_s_barrier();
    COMPUTE(s);

    // epilogue: D col = lane&15, row = (lane>>4)*4 + r   [m89-verified layout]
    const int en = (int)bn0 + wn + lr;
    const int em = (int)bm0 + wm + (lane >> 4) * 4;
#pragma unroll
    for (int mi = 0; mi < 8; ++mi)
#pragma unroll
        for (int ni = 0; ni < 4; ++ni)
#pragma unroll
            for (int r = 0; r < 4; ++r)
                C[(size_t)(em + mi * 16 + r) * N + (en + ni * 16)] = acc[mi][ni][r];
}

// stage B: split-K partials, partial z at C + z*H*H (no atomics)
__global__ __launch_bounds__(512, 2) void gemm_kb_part(const u16* __restrict__ A,
                                                       const u16* __restrict__ B,
                                                       float* __restrict__ C,
                                                       int lda, int ldb, int N, int klen) {
    gemm256_core(A, B, C + (size_t)blockIdx.z * H * H, lda, ldb, N, klen);
}

// stage C: plain store
__global__ __launch_bounds__(512, 2) void gemm_kc_store(const u16* __restrict__ A,
                                                        const u16* __restrict__ B,
                                                        float* __restrict__ C,
                                                        int lda, int ldb, int N, int klen) {
    gemm256_core(A, B, C, lda, ldb, N, klen);
}

// ---------------- LayerNorm in-place over rows of 2048 fp32 ----------------
__global__ __launch_bounds__(256) void layernorm_kernel(float* __restrict__ h,
                                                        const float* __restrict__ gamma,
                                                        const float* __restrict__ beta) {
    const int t = threadIdx.x;
    float* row = h + (size_t)blockIdx.x * H;
    float4 v0 = ((const float4*)row)[t];
    float4 v1 = ((const float4*)row)[t + 256];
    float s = v0.x + v0.y + v0.z + v0.w + v1.x + v1.y + v1.z + v1.w;
    float q = v0.x * v0.x + v0.y * v0.y + v0.z * v0.z + v0.w * v0.w +
              v1.x * v1.x + v1.y * v1.y + v1.z * v1.z + v1.w * v1.w;
#pragma unroll
    for (int off = 32; off > 0; off >>= 1) {
        s += __shfl_down(s, off, 64);
        q += __shfl_down(q, off, 64);
    }
    __shared__ float sw[4], sq[4];
    if ((t & 63) == 0) { sw[t >> 6] = s; sq[t >> 6] = q; }
    __syncthreads();
    s = sw[0] + sw[1] + sw[2] + sw[3];
    q = sq[0] + sq[1] + sq[2] + sq[3];
    float mu = s * (1.0f / H);
    float var = q * (1.0f / H) - mu * mu;
    float rs = rsqrtf(var + 1e-5f);
    float4 g0 = ((const float4*)gamma)[t], g1 = ((const float4*)gamma)[t + 256];
    float4 b0 = ((const float4*)beta)[t],  b1 = ((const float4*)beta)[t + 256];
    v0.x = (v0.x - mu) * rs * g0.x + b0.x;
    v0.y = (v0.y - mu) * rs * g0.y + b0.y;
    v0.z = (v0.z - mu) * rs * g0.z + b0.z;
    v0.w = (v0.w - mu) * rs * g0.w + b0.w;
    v1.x = (v1.x - mu) * rs * g1.x + b1.x;
    v1.y = (v1.y - mu) * rs * g1.y + b1.y;
    v1.z = (v1.z - mu) * rs * g1.z + b1.z;
    v1.w = (v1.w - mu) * rs * g1.w + b1.w;
    ((float4*)row)[t] = v0;
    ((float4*)row)[t + 256] = v1;
}

extern "C" void kernel_launch(void* const* d_in, const int* in_sizes, int n_in,
                              void* d_out, int out_size, void* d_ws, size_t ws_size,
                              hipStream_t stream) {
    const float* x     = (const float*)d_in[0];
    const float* w_qkv = (const float*)d_in[1];
    const float* s_qkv = (const float*)d_in[2];
    const float* w_z   = (const float*)d_in[3];
    const float* s_z   = (const float*)d_in[4];
    const float* w_b   = (const float*)d_in[5];
    const float* s_b   = (const float*)d_in[6];
    const float* w_a   = (const float*)d_in[7];
    const float* s_a   = (const float*)d_in[8];
    const float* dq    = (const float*)d_in[9];
    const float* dz    = (const float*)d_in[10];
    const float* db    = (const float*)d_in[11];
    const float* da    = (const float*)d_in[12];
    const float* gamma = (const float*)d_in[13];
    const float* beta  = (const float*)d_in[14];
    float* out = (float*)d_out;

    // workspace layout (bytes) — 159.4 MB total:
    //   A_cat bf16 [2048][14336]  @ 0          (58,720,256)
    //   B_cat bf16 [2048][14336]  @ 58720256   (58,720,256)
    //   Xb    bf16 [8192][2048]   @ 117440512  (33,554,432)
    //   G     bf16 [2048][2048]   @ 150994944  (8,388,608)
    // split-K fp32 partials: 4 x 16.8 MB in d_out (exactly out_size).
    uint8_t* ws = (uint8_t*)d_ws;
    u16* Acat = (u16*)(ws);
    u16* Bcat = (u16*)(ws + 58720256);
    u16* Xb   = (u16*)(ws + 117440512);
    u16* G    = (u16*)(ws + 150994944);

    // prep: pack d's + cast x (fused), transpose+scale w's
    prep_pack<<<36864, 256, 0, stream>>>(dq, dz, db, da, x, Acat, Xb);
    prep_w<<<dim3(32, 224), 256, 0, stream>>>(w_qkv, s_qkv, w_z, s_z,
                                              w_b, s_b, w_a, s_a, Bcat);
    // stage B: partial_z = A_cat @ B_cat^T over K-chunk z (K=14336, 4 x 3584)
    // 8x8 tiles of 256^2 x 4 K-splits = 256 WGs = 1 block/CU
    gemm_kb_part<<<dim3(8, 8, 4), 512, 0, stream>>>(Acat, Bcat, out, KTOT, KTOT, H, 3584);
    // reduce partials -> G bf16
    reduce4_cvt<<<4096, 256, 0, stream>>>(out, G);
    // stage C: h = Xb @ G^T  (M=8192, N=2048, K=2048) -> d_out fp32; 32x8 = 256 WGs
    gemm_kc_store<<<dim3(8, 32, 1), 512, 0, stream>>>(Xb, G, out, H, H, H, H);
    // LayerNorm in-place
    layernorm_kernel<<<8192, 256, 0, stream>>>(out, gamma, beta);
}

// Round 2
// 537.807 us; speedup vs baseline: 1.0955x; 1.0955x over previous
//
#include <hip/hip_runtime.h>
#include <hip/hip_bf16.h>
#include <stdint.h>

// FourBranchFork: h = sum_b (x @ ws_b.T) @ d_b.T ; LN(h)
// Collapsed: G[j,i] = sum_b sum_k d_b[j,k]*ws_b[k,i]  (2048x2048, K=14336)
//            h[n,j] = sum_i x[n,i]*G[j,i]             (8192x2048, K=2048)
// R6: faithful m201-style 8-phase 256x256 core. BK=64 full-tile dbuf (128 KiB),
//     quadrant phasing (16 MFMA/phase), B-frags held in regs (24 ds_read/tile),
//     counted vmcnt(4)/vmcnt(2) never 0 in main loop, setprio on MFMA cluster,
//     bijective XCD swizzle -> K-synced 4x8 panel clusters per XCD L2.

typedef unsigned short u16;
typedef __bf16 bf16x8 __attribute__((ext_vector_type(8)));
typedef float f32x4 __attribute__((ext_vector_type(4)));

#define H 2048
#define KTOT 14336

__device__ __forceinline__ u16 f2b(float f) {
    union { float f; uint32_t u; } v; v.f = f;
    uint32_t u = v.u;
    return (u16)((u + 0x7fffu + ((u >> 16) & 1u)) >> 16);  // RNE
}

__device__ __forceinline__ void gld16(const u16* g, u16* l) {
    __builtin_amdgcn_global_load_lds((__attribute__((address_space(1))) void*)g,
                                     (__attribute__((address_space(3))) void*)l,
                                     16, 0, 0);
}

// ---- fused relayout: pack d_b's -> A_cat bf16, cast x -> Xb bf16 ----
__global__ __launch_bounds__(256) void prep_pack(const float* __restrict__ dq,
                                                 const float* __restrict__ dz,
                                                 const float* __restrict__ db,
                                                 const float* __restrict__ da,
                                                 const float* __restrict__ x,
                                                 u16* __restrict__ Acat,
                                                 u16* __restrict__ Xb) {
    int bid = blockIdx.x;
    if (bid >= 28672) {   // cast x: 8 elems/thread
        size_t i = (((size_t)(bid - 28672)) * 256 + threadIdx.x) * 8;
        float4 a = *(const float4*)(x + i);
        float4 b = *(const float4*)(x + i + 4);
        uint32_t p0 = (uint32_t)f2b(a.x) | ((uint32_t)f2b(a.y) << 16);
        uint32_t p1 = (uint32_t)f2b(a.z) | ((uint32_t)f2b(a.w) << 16);
        uint32_t p2 = (uint32_t)f2b(b.x) | ((uint32_t)f2b(b.y) << 16);
        uint32_t p3 = (uint32_t)f2b(b.z) | ((uint32_t)f2b(b.w) << 16);
        *(uint4*)(Xb + i) = make_uint4(p0, p1, p2, p3);
        return;
    }
    const float* src; int kshift, kmask, coloff, base;
    if (bid < 16384)      { src = dq; kshift = 13; kmask = 8191; coloff = 0;     base = 0; }
    else if (bid < 24576) { src = dz; kshift = 12; kmask = 4095; coloff = 8192;  base = 16384; }
    else if (bid < 26624) { src = db; kshift = 10; kmask = 1023; coloff = 12288; base = 24576; }
    else                  { src = da; kshift = 10; kmask = 1023; coloff = 13312; base = 26624; }
    size_t idx = ((size_t)(bid - base) * 256 + threadIdx.x) * 4;
    int r = (int)(idx >> kshift);
    int c = (int)(idx & (size_t)kmask);
    float4 v = *(const float4*)(src + idx);
    ushort4 o = make_ushort4(f2b(v.x), f2b(v.y), f2b(v.z), f2b(v.w));
    *(ushort4*)(Acat + (size_t)r * KTOT + coloff + c) = o;
}

// ---- transpose+scale w_b [Kb,2048] fp32 * s -> B_cat[i][coloff+k] bf16 ----
__global__ __launch_bounds__(256) void prep_w(const float* __restrict__ wq, const float* __restrict__ sq,
                                              const float* __restrict__ wz, const float* __restrict__ sz,
                                              const float* __restrict__ wb, const float* __restrict__ sb,
                                              const float* __restrict__ wa, const float* __restrict__ sa,
                                              u16* __restrict__ dst) {
    __shared__ float tile[64][65];
    int by = blockIdx.y;
    const float* w; const float* s; int coloff, ybase;
    if (by < 128)      { w = wq; s = sq; coloff = 0;     ybase = 0; }
    else if (by < 192) { w = wz; s = sz; coloff = 8192;  ybase = 128; }
    else if (by < 208) { w = wb; s = sb; coloff = 12288; ybase = 192; }
    else               { w = wa; s = sa; coloff = 13312; ybase = 208; }
    const int t = threadIdx.x;
    const int i0 = blockIdx.x * 64, k0 = (by - ybase) * 64;
    const int c4 = (t & 15) * 4;
    const int r0 = t >> 4;
    const int sib = i0 >> 7;
#pragma unroll
    for (int rr = 0; rr < 4; ++rr) {
        int r = r0 + rr * 16;
        float sc = s[((k0 + r) >> 7) * (H / 128) + sib];
        float4 v = *(const float4*)(w + (size_t)(k0 + r) * H + i0 + c4);
        tile[r][c4 + 0] = v.x * sc;
        tile[r][c4 + 1] = v.y * sc;
        tile[r][c4 + 2] = v.z * sc;
        tile[r][c4 + 3] = v.w * sc;
    }
    __syncthreads();
#pragma unroll
    for (int rr = 0; rr < 4; ++rr) {
        int i = r0 + rr * 16;
        ushort4 o = make_ushort4(f2b(tile[c4 + 0][i]), f2b(tile[c4 + 1][i]),
                                 f2b(tile[c4 + 2][i]), f2b(tile[c4 + 3][i]));
        *(ushort4*)(dst + (size_t)(i0 + i) * KTOT + coloff + k0 + c4) = o;
    }
}

// ---- reduce 4 split-K fp32 partials -> G bf16 ----
__global__ __launch_bounds__(256) void reduce4_cvt(const float* __restrict__ P,
                                                   u16* __restrict__ G) {
    size_t i = ((size_t)blockIdx.x * 256 + threadIdx.x) * 4;
    const size_t st = (size_t)H * H;
    float4 a = *(const float4*)(P + i);
    float4 b = *(const float4*)(P + i + st);
    float4 c = *(const float4*)(P + i + 2 * st);
    float4 d = *(const float4*)(P + i + 3 * st);
    ushort4 o = make_ushort4(f2b(a.x + b.x + c.x + d.x),
                             f2b(a.y + b.y + c.y + d.y),
                             f2b(a.z + b.z + c.z + d.z),
                             f2b(a.w + b.w + c.w + d.w));
    *(ushort4*)(G + i) = o;
}

// ---------------- GEMM core (B^T form): C[m,n] = sum_k A[m,k]*B[n,k] ----------------
// 256x256 tile, 8 waves (2M x 4N), 512 threads. BK=64, full-tile double-buffer:
// per op 2 x [256 rows][64 k] bf16 (32 KB), 128 KiB total.
// Swizzle (both-sides involution): 16-B chunk c of a 128-B row stored at
// physical chunk c ^ (row&7). Staging pre-swizzles the GLOBAL source address
// (gld_lds dest stays lane-linear); frag ds_read applies the same XOR.
// Schedule per K-tile t (4 phases, each: [ds_reads | 2 stage-rounds of t+1] ->
// barrier -> setprio(1) 16 MFMA setprio(0) -> barrier):
//   P0: rd A[qm0](8) + B[qn0](4) ; stage B rows 0-63,64-127   ; MFMA (0,0)
//   P1: rd B[qn1](4)             ; stage B rows 128-191,192-255; vmcnt(4); MFMA (0,1)
//   P2: rd A[qm1](8)             ; stage A rows 0-63,128-191  ; MFMA (1,1)
//   P3: (B held in regs)         ; stage A rows 64-127,192-255; vmcnt(2); MFMA (1,0)
// Boundary invariant: at each tile entry the last 2 rounds (A rows 64-127/192-255)
// may still be in flight; they are only needed at P2 and are drained by P1's
// vmcnt(4). vmcnt never reaches 0 in the main loop (T3+T4).
__device__ __forceinline__ void gemm256_core(const u16* __restrict__ A,
                                             const u16* __restrict__ B,
                                             float* __restrict__ C,
                                             int lda, int ldb, int N, int klen,
                                             int bm0, int bn0, int kstart) {
    __shared__ __align__(16) u16 As[2][16384];   // 64 KB
    __shared__ __align__(16) u16 Bs[2][16384];   // 64 KB
    const int t = threadIdx.x;                   // 0..511
    const int lane = t & 63;
    const int wave = t >> 6;                     // 0..7
    const int wm = (wave >> 2) * 128;            // 0 / 128
    const int wn = (wave & 3) * 64;              // 0/64/128/192
    const int NT = klen >> 6;

    // staging geometry: round = 64 rows x 64 k = 8 KB (1 gld16 per thread).
    // thread t -> row srow = t>>3 (within round), physical chunk t&7,
    // global chunk (t&7)^((t>>3)&7)  [srow&7 == (t>>3)&7].
    const int srow = t >> 3;
    const int sc = ((t & 7) ^ ((t >> 3) & 7)) * 8;
    const u16* gA = A + (size_t)(bm0 + srow) * lda + kstart + sc;
    const u16* gB = B + (size_t)(bn0 + srow) * ldb + kstart + sc;
    const size_t a64 = (size_t)64 * lda, b64 = (size_t)64 * ldb;
    u16* const lA = (u16*)As + (t & ~63) * 8;    // + wbuf*16384 + rb*4096
    u16* const lB = (u16*)Bs + (t & ~63) * 8;

    // fragment read offsets (u16 units): physical chunk = (kh*4+kc) ^ (row&7),
    // row&7 == lane&7 for all frags (all row bases are multiples of 8).
    const int lr = lane & 15;
    const int ch0 = (((lane >> 4)    ) ^ (lane & 7)) * 8;   // kh=0
    const int ch1 = (((lane >> 4) | 4) ^ (lane & 7)) * 8;   // kh=1

    f32x4 a00[4][2] = {}, a01[4][2] = {}, a10[4][2] = {}, a11[4][2] = {};
    bf16x8 aF[4][2], b0F[2][2], b1F[2][2];

    auto RD_A = [&](const u16* buf, int qm) {
#pragma unroll
        for (int f = 0; f < 4; ++f) {
            const u16* p = buf + (wm + qm * 64 + f * 16 + lr) * 64;
            aF[f][0] = *(const bf16x8*)(p + ch0);
            aF[f][1] = *(const bf16x8*)(p + ch1);
        }
    };
    auto RD_B = [&](const u16* buf, int qn) {
#pragma unroll
        for (int g = 0; g < 2; ++g) {
            const u16* p = buf + (wn + qn * 32 + g * 16 + lr) * 64;
            if (qn == 0) { b0F[g][0] = *(const bf16x8*)(p + ch0);
                           b0F[g][1] = *(const bf16x8*)(p + ch1); }
            else         { b1F[g][0] = *(const bf16x8*)(p + ch0);
                           b1F[g][1] = *(const bf16x8*)(p + ch1); }
        }
    };
    auto MM = [&](int qm, int qn) {
        __builtin_amdgcn_s_setprio(1);
#pragma unroll
        for (int f = 0; f < 4; ++f)
#pragma unroll
            for (int g = 0; g < 2; ++g) {
                f32x4& d = (qm == 0) ? (qn == 0 ? a00[f][g] : a01[f][g])
                                     : (qn == 0 ? a10[f][g] : a11[f][g]);
                const bf16x8* bb = (qn == 0) ? b0F[g] : b1F[g];
                d = __builtin_amdgcn_mfma_f32_16x16x32_bf16(aF[f][0], bb[0], d, 0, 0, 0);
                d = __builtin_amdgcn_mfma_f32_16x16x32_bf16(aF[f][1], bb[1], d, 0, 0, 0);
            }
        __builtin_amdgcn_s_setprio(0);
    };
    // round rnd: 0-3 = B rows rnd*64 ; 4 = A rows 0 ; 5 = A rows 128 ;
    //            6 = A rows 64 ; 7 = A rows 192. (rb in 64-row units)
    auto STG = [&](int wbuf, int rnd, int kt) {
        if (rnd < 4)
            gld16(gB + (size_t)rnd * b64 + kt, lB + wbuf * 16384 + rnd * 4096);
        else {
            const int rb = (rnd == 4) ? 0 : (rnd == 5) ? 2 : (rnd == 6) ? 1 : 3;
            gld16(gA + (size_t)rb * a64 + kt, lA + wbuf * 16384 + rb * 4096);
        }
    };

    // prologue: stage tile 0, drain all but last 2 rounds (A rows 64-127/192-255)
#pragma unroll
    for (int r = 0; r < 8; ++r) STG(0, r, 0);
    asm volatile("s_waitcnt vmcnt(2)" ::: "memory");
    __builtin_amdgcn_s_barrier();
    asm volatile("" ::: "memory");

    for (int tt = 0; tt < NT; ++tt) {
        const u16* Ar = (const u16*)As + (tt & 1) * 16384;
        const u16* Br = (const u16*)Bs + (tt & 1) * 16384;
        const int wbuf = (tt + 1) & 1;
        const int ktn = (tt + 1) * 64;
        const bool st = (tt + 1) < NT;
        // ---- P0: quadrant (0,0)
        RD_A(Ar, 0); RD_B(Br, 0);
        if (st) { STG(wbuf, 0, ktn); STG(wbuf, 1, ktn); }
        __builtin_amdgcn_s_barrier(); asm volatile("" ::: "memory");
        MM(0, 0);
        __builtin_amdgcn_s_barrier(); asm volatile("" ::: "memory");
        // ---- P1: quadrant (0,1)
        RD_B(Br, 1);
        if (st) { STG(wbuf, 2, ktn); STG(wbuf, 3, ktn);
                  asm volatile("s_waitcnt vmcnt(4)" ::: "memory"); }
        else    { asm volatile("s_waitcnt vmcnt(0)" ::: "memory"); }
        __builtin_amdgcn_s_barrier(); asm volatile("" ::: "memory");
        MM(0, 1);
        __builtin_amdgcn_s_barrier(); asm volatile("" ::: "memory");
        // ---- P2: quadrant (1,1)   (needs A rows 64-127/192-255: just drained)
        RD_A(Ar, 1);
        if (st) { STG(wbuf, 4, ktn); STG(wbuf, 5, ktn); }
        __builtin_amdgcn_s_barrier(); asm volatile("" ::: "memory");
        MM(1, 1);
        __builtin_amdgcn_s_barrier(); asm volatile("" ::: "memory");
        // ---- P3: quadrant (1,0)   (B0 held in regs since P0)
        if (st) { STG(wbuf, 6, ktn); STG(wbuf, 7, ktn);
                  asm volatile("s_waitcnt vmcnt(2)" ::: "memory"); }
        __builtin_amdgcn_s_barrier(); asm volatile("" ::: "memory");
        MM(1, 0);
        __builtin_amdgcn_s_barrier(); asm volatile("" ::: "memory");
    }

    // epilogue: D col = lane&15, row = (lane>>4)*4 + r   [m89-verified layout]
    const int en = bn0 + wn + lr;
    const int em0 = bm0 + wm + (lane >> 4) * 4;
#pragma unroll
    for (int f = 0; f < 4; ++f)
#pragma unroll
        for (int g = 0; g < 2; ++g)
#pragma unroll
            for (int r = 0; r < 4; ++r) {
                C[(size_t)(em0 + f * 16 + r) * N + en + g * 16]            = a00[f][g][r];
                C[(size_t)(em0 + f * 16 + r) * N + en + 32 + g * 16]      = a01[f][g][r];
                C[(size_t)(em0 + 64 + f * 16 + r) * N + en + g * 16]      = a10[f][g][r];
                C[(size_t)(em0 + 64 + f * 16 + r) * N + en + 32 + g * 16] = a11[f][g][r];
            }
}

// stage B: split-K partials at C + z*H*H (no atomics). 256 blocks, XCD-swizzled:
// dispatch i -> logical L=(i%8)*32+i/8 so each XCD gets a K-synced 4x8 cluster.
__global__ __launch_bounds__(512, 2) void gemm_kb_part(const u16* __restrict__ A,
                                                       const u16* __restrict__ B,
                                                       float* __restrict__ C,
                                                       int lda, int ldb, int N, int klen) {
    int L = ((blockIdx.x & 7) << 5) + (blockIdx.x >> 3);
    int bx = L & 7, by = (L >> 3) & 7, bz = L >> 6;
    gemm256_core(A, B, C + (size_t)bz * H * H, lda, ldb, N, klen,
                 by * 256, bx * 256, bz * klen);
}

// stage C: plain store. 256 blocks (8 x 32), same swizzle.
__global__ __launch_bounds__(512, 2) void gemm_kc_store(const u16* __restrict__ A,
                                                        const u16* __restrict__ B,
                                                        float* __restrict__ C,
                                                        int lda, int ldb, int N, int klen) {
    int L = ((blockIdx.x & 7) << 5) + (blockIdx.x >> 3);
    int bx = L & 7, by = L >> 3;
    gemm256_core(A, B, C, lda, ldb, N, klen, by * 256, bx * 256, 0);
}

// ---------------- LayerNorm in-place over rows of 2048 fp32 ----------------
__global__ __launch_bounds__(256) void layernorm_kernel(float* __restrict__ h,
                                                        const float* __restrict__ gamma,
                                                        const float* __restrict__ beta) {
    const int t = threadIdx.x;
    float* row = h + (size_t)blockIdx.x * H;
    float4 v0 = ((const float4*)row)[t];
    float4 v1 = ((const float4*)row)[t + 256];
    float s = v0.x + v0.y + v0.z + v0.w + v1.x + v1.y + v1.z + v1.w;
    float q = v0.x * v0.x + v0.y * v0.y + v0.z * v0.z + v0.w * v0.w +
              v1.x * v1.x + v1.y * v1.y + v1.z * v1.z + v1.w * v1.w;
#pragma unroll
    for (int off = 32; off > 0; off >>= 1) {
        s += __shfl_down(s, off, 64);
        q += __shfl_down(q, off, 64);
    }
    __shared__ float sw[4], sq[4];
    if ((t & 63) == 0) { sw[t >> 6] = s; sq[t >> 6] = q; }
    __syncthreads();
    s = sw[0] + sw[1] + sw[2] + sw[3];
    q = sq[0] + sq[1] + sq[2] + sq[3];
    float mu = s * (1.0f / H);
    float var = q * (1.0f / H) - mu * mu;
    float rs = rsqrtf(var + 1e-5f);
    float4 g0 = ((const float4*)gamma)[t], g1 = ((const float4*)gamma)[t + 256];
    float4 b0 = ((const float4*)beta)[t],  b1 = ((const float4*)beta)[t + 256];
    v0.x = (v0.x - mu) * rs * g0.x + b0.x;
    v0.y = (v0.y - mu) * rs * g0.y + b0.y;
    v0.z = (v0.z - mu) * rs * g0.z + b0.z;
    v0.w = (v0.w - mu) * rs * g0.w + b0.w;
    v1.x = (v1.x - mu) * rs * g1.x + b1.x;
    v1.y = (v1.y - mu) * rs * g1.y + b1.y;
    v1.z = (v1.z - mu) * rs * g1.z + b1.z;
    v1.w = (v1.w - mu) * rs * g1.w + b1.w;
    ((float4*)row)[t] = v0;
    ((float4*)row)[t + 256] = v1;
}

extern "C" void kernel_launch(void* const* d_in, const int* in_sizes, int n_in,
                              void* d_out, int out_size, void* d_ws, size_t ws_size,
                              hipStream_t stream) {
    const float* x     = (const float*)d_in[0];
    const float* w_qkv = (const float*)d_in[1];
    const float* s_qkv = (const float*)d_in[2];
    const float* w_z   = (const float*)d_in[3];
    const float* s_z   = (const float*)d_in[4];
    const float* w_b   = (const float*)d_in[5];
    const float* s_b   = (const float*)d_in[6];
    const float* w_a   = (const float*)d_in[7];
    const float* s_a   = (const float*)d_in[8];
    const float* dq    = (const float*)d_in[9];
    const float* dz    = (const float*)d_in[10];
    const float* db    = (const float*)d_in[11];
    const float* da    = (const float*)d_in[12];
    const float* gamma = (const float*)d_in[13];
    const float* beta  = (const float*)d_in[14];
    float* out = (float*)d_out;

    // workspace layout (bytes) — 159.4 MB total:
    //   A_cat bf16 [2048][14336]  @ 0          (58,720,256)
    //   B_cat bf16 [2048][14336]  @ 58720256   (58,720,256)
    //   Xb    bf16 [8192][2048]   @ 117440512  (33,554,432)
    //   G     bf16 [2048][2048]   @ 150994944  (8,388,608)
    // split-K fp32 partials: 4 x 16.8 MB in d_out (exactly out_size).
    uint8_t* ws = (uint8_t*)d_ws;
    u16* Acat = (u16*)(ws);
    u16* Bcat = (u16*)(ws + 58720256);
    u16* Xb   = (u16*)(ws + 117440512);
    u16* G    = (u16*)(ws + 150994944);

    prep_pack<<<36864, 256, 0, stream>>>(dq, dz, db, da, x, Acat, Xb);
    prep_w<<<dim3(32, 224), 256, 0, stream>>>(w_qkv, s_qkv, w_z, s_z,
                                              w_b, s_b, w_a, s_a, Bcat);
    // stage B: 8x8 tiles of 256^2 x 4 K-splits = 256 WGs (1 block/CU)
    gemm_kb_part<<<256, 512, 0, stream>>>(Acat, Bcat, out, KTOT, KTOT, H, 3584);
    reduce4_cvt<<<4096, 256, 0, stream>>>(out, G);
    // stage C: h = Xb @ G^T  (M=8192, N=2048, K=2048); 8x32 = 256 WGs
    gemm_kc_store<<<256, 512, 0, stream>>>(Xb, G, out, H, H, H, H);
    layernorm_kernel<<<8192, 256, 0, stream>>>(out, gamma, beta);
}